// Round 1
// baseline (281.693 us; speedup 1.0000x reference)
//
#include <hip/hip_runtime.h>
#include <cstdint>
#include <cstddef>

// DenseGAT, N=4096, IN_DIM=256, H=4, D=64, NEG_SLOPE=0.2
// w[i,j,h] = eb * max(t5, tt);  tt = ui*uj = exp(.2(ei+ej)),
//   t5 = ui5*uj5 = exp(ei+ej) = tt^5 (exact inputs), eb = exp(bias) or 0.
// max trick: tt>1 => t5>tt, tt<1 => t5<tt, so select == max. Row sums via
// an extra MFMA against a ones-B fragment (no serial VALU add chain).
//
// R1: gat_attn was latency-bound (MfmaUtil 7%, VALU 14%, HBM 17%, occ 37%).
//  - i-tile 32 -> 16 rows: grid 1024 -> 2048 blocks (8 blocks/CU, occ -> 100%).
//  - T14 async-stage split: issue next-chunk bias loads right after the
//    barrier, consume (expf + LDS write) only after the MFMA s-loop, so the
//    HBM/L3 latency hides under compute instead of stalling each chunk.

typedef _Float16 f16x4 __attribute__((ext_vector_type(4)));
typedef _Float16 f16x8 __attribute__((ext_vector_type(8)));
typedef float f32x4 __attribute__((ext_vector_type(4)));

#define NN 4096

// ---- Kernel 1: Wh = h @ W (fp32) + Vt (fp16 transpose) + ui/uj exps ------
// grid (4 heads, 128 row-tiles of 32), block 256.
__global__ __launch_bounds__(256) void gemm_wh(
    const float* __restrict__ A, const float* __restrict__ Bw,
    const float* __restrict__ av, float* __restrict__ C,
    _Float16* __restrict__ Vt,
    _Float16* __restrict__ uit, _Float16* __restrict__ ui5t,
    _Float16* __restrict__ ujt, _Float16* __restrict__ uj5t) {
  __shared__ float sA[32][36];      // [k][row]
  __shared__ float sB[32][68];      // [k][col]
  __shared__ _Float16 sT[64][40];   // transpose staging
  const int h  = blockIdx.x;
  const int by = blockIdx.y;
  const int t  = threadIdx.x;
  const int row0 = by * 32, col0 = h * 64;
  const int tc = t & 15, tr = t >> 4;      // cols tc*4..+3, rows tr*2..+1
  float acc[2][4];
  #pragma unroll
  for (int q = 0; q < 2; q++)
    #pragma unroll
    for (int p = 0; p < 4; p++) acc[q][p] = 0.f;

  for (int k0 = 0; k0 < 256; k0 += 32) {
    __syncthreads();
    {
      const int r = t >> 3, k4 = (t & 7) * 4;      // A: 32x32
      float4 v = *(const float4*)&A[(size_t)(row0 + r) * 256 + k0 + k4];
      sA[k4 + 0][r] = v.x; sA[k4 + 1][r] = v.y;
      sA[k4 + 2][r] = v.z; sA[k4 + 3][r] = v.w;
    }
    #pragma unroll
    for (int q = 0; q < 2; q++) {                   // B: 32x64
      const int u = t + q * 256;
      const int kr = u >> 4, c4 = (u & 15) * 4;
      *(float4*)&sB[kr][c4] =
          *(const float4*)&Bw[(size_t)(k0 + kr) * 256 + col0 + c4];
    }
    __syncthreads();
    #pragma unroll
    for (int kk = 0; kk < 32; kk++) {
      float2 a2 = *(const float2*)&sA[kk][tr * 2];
      float4 bv = *(const float4*)&sB[kk][tc * 4];
      const float bp[4] = {bv.x, bv.y, bv.z, bv.w};
      #pragma unroll
      for (int p = 0; p < 4; p++) {
        acc[0][p] = fmaf(a2.x, bp[p], acc[0][p]);
        acc[1][p] = fmaf(a2.y, bp[p], acc[1][p]);
      }
    }
  }
  // C store (fp32 Wh)
  #pragma unroll
  for (int q = 0; q < 2; q++) {
    float4 v = make_float4(acc[q][0], acc[q][1], acc[q][2], acc[q][3]);
    *(float4*)&C[(size_t)(row0 + tr * 2 + q) * 256 + col0 + tc * 4] = v;
  }
  // ei/ej: dot with a_i, a_j over the 64 cols of this head
  {
    float pi[2] = {0.f, 0.f}, pj[2] = {0.f, 0.f};
    #pragma unroll
    for (int q = 0; q < 2; q++)
      #pragma unroll
      for (int p = 0; p < 4; p++) {
        const int d = tc * 4 + p;
        pi[q] = fmaf(acc[q][p], av[h * 128 + d], pi[q]);
        pj[q] = fmaf(acc[q][p], av[h * 128 + 64 + d], pj[q]);
      }
    #pragma unroll
    for (int m = 1; m <= 8; m <<= 1) {
      #pragma unroll
      for (int q = 0; q < 2; q++) {
        pi[q] += __shfl_xor(pi[q], m, 64);
        pj[q] += __shfl_xor(pj[q], m, 64);
      }
    }
    if (tc == 0) {
      #pragma unroll
      for (int q = 0; q < 2; q++) {
        const int row = row0 + tr * 2 + q;
        uit [(size_t)h * NN + row] = (_Float16)__expf(0.2f * pi[q]);
        ui5t[(size_t)h * NN + row] = (_Float16)__expf(pi[q]);       // = ui^5
        ujt [(size_t)h * NN + row] = (_Float16)__expf(0.2f * pj[q]);
        uj5t[(size_t)h * NN + row] = (_Float16)__expf(pj[q]);       // = uj^5
      }
    }
  }
  // Vt transpose: Vt[col0+d][row0+j] fp16
  #pragma unroll
  for (int q = 0; q < 2; q++)
    #pragma unroll
    for (int p = 0; p < 4; p++)
      sT[tc * 4 + p][tr * 2 + q] = (_Float16)acc[q][p];
  __syncthreads();
  {
    const int dd = t >> 2, j8 = (t & 3) * 8;
    f16x8 w;
    #pragma unroll
    for (int k = 0; k < 8; k++) w[k] = sT[dd][j8 + k];
    *(f16x8*)&Vt[(size_t)(col0 + dd) * NN + row0 + j8] = w;
  }
}

// ---- Kernel 2: fused masked-softmax attention (MFMA) ---------------------
// grid (256 i-tiles of 16, CH j-chunks), block 256 = 4 waves (wave = head).
__global__ __launch_bounds__(256, 8) void gat_attn(
    const float* __restrict__ bias, const _Float16* __restrict__ Vt,
    const _Float16* __restrict__ uit, const _Float16* __restrict__ ui5t,
    const _Float16* __restrict__ ujt, const _Float16* __restrict__ uj5t,
    float* __restrict__ P, float* __restrict__ L, int jpc) {
  __shared__ _Float16 seb[2][16][136];   // exp(bias) tile [i][j], pad 8
  const int itile = blockIdx.x;
  const int chunk = blockIdx.y;
  const int tid = threadIdx.x;
  const int lane = tid & 63;
  const int h = __builtin_amdgcn_readfirstlane(tid >> 6);
  const int m = lane & 15;
  const int quad = lane >> 4;
  const int i0 = itile * 16;
  const int j0 = chunk * jpc;
  const int nc = jpc >> 7;

  f32x4 acc[5];                          // [dt0..3, ones-col]
  #pragma unroll
  for (int dt = 0; dt < 5; dt++)
    #pragma unroll
    for (int r = 0; r < 4; r++) acc[dt][r] = 0.f;

  const _Float16 ui_v = uit [(size_t)h * NN + i0 + m];
  const _Float16 u5_v = ui5t[(size_t)h * NN + i0 + m];
  const f16x8 ui8 = {ui_v, ui_v, ui_v, ui_v, ui_v, ui_v, ui_v, ui_v};
  const f16x8 u58 = {u5_v, u5_v, u5_v, u5_v, u5_v, u5_v, u5_v, u5_v};
  const f16x8 kOne = {(_Float16)1.f, (_Float16)1.f, (_Float16)1.f, (_Float16)1.f,
                      (_Float16)1.f, (_Float16)1.f, (_Float16)1.f, (_Float16)1.f};

  // async-stage split: load_chunk issues the bias loads into regs; fill
  // consumes them (expf + LDS write) only after the compute phase.
  const int sr = tid >> 4, sf = tid & 15;   // 16 rows x (16 thr * 8 cols)
  const float* bp0 = bias + (size_t)(i0 + sr) * NN + j0 + sf * 4;
  float4 pf0, pf1;
  auto load_chunk = [&](int jc) {
    const float* bp = bp0 + jc * 128;
    pf0 = *(const float4*)(bp);
    pf1 = *(const float4*)(bp + 64);
  };
  auto fill = [&](int buf) {
    f16x4 e0v, e1v;
    e0v[0] = (_Float16)((pf0.x == 0.f) ? 0.f : __expf(pf0.x));
    e0v[1] = (_Float16)((pf0.y == 0.f) ? 0.f : __expf(pf0.y));
    e0v[2] = (_Float16)((pf0.z == 0.f) ? 0.f : __expf(pf0.z));
    e0v[3] = (_Float16)((pf0.w == 0.f) ? 0.f : __expf(pf0.w));
    e1v[0] = (_Float16)((pf1.x == 0.f) ? 0.f : __expf(pf1.x));
    e1v[1] = (_Float16)((pf1.y == 0.f) ? 0.f : __expf(pf1.y));
    e1v[2] = (_Float16)((pf1.z == 0.f) ? 0.f : __expf(pf1.z));
    e1v[3] = (_Float16)((pf1.w == 0.f) ? 0.f : __expf(pf1.w));
    *(f16x4*)&seb[buf][sr][sf * 4] = e0v;
    *(f16x4*)&seb[buf][sr][sf * 4 + 64] = e1v;
  };

  load_chunk(0);
  fill(0);

  for (int jc = 0; jc < nc; jc++) {
    const int buf = jc & 1;
    __syncthreads();
    if (jc + 1 < nc) load_chunk(jc + 1);   // issue early, consume late

    const _Float16* vb  = Vt + (size_t)(h * 64 + m) * NN + j0 + jc * 128 + quad * 8;
    const _Float16* ujb = ujt  + (size_t)h * NN + j0 + jc * 128 + quad * 8;
    const _Float16* u5b = uj5t + (size_t)h * NN + j0 + jc * 128 + quad * 8;

    f16x8 bc[4], bn[4];
    #pragma unroll
    for (int dt = 0; dt < 4; dt++)
      bc[dt] = *(const f16x8*)(vb + (size_t)(dt * 16) * NN);

    #pragma unroll
    for (int s = 0; s < 4; s++) {
      if (s < 3) {
        #pragma unroll
        for (int dt = 0; dt < 4; dt++)
          bn[dt] = *(const f16x8*)(vb + (size_t)(dt * 16) * NN + (s + 1) * 32);
      }
      const f16x8 uj8  = *(const f16x8*)(ujb + s * 32);
      const f16x8 uj58 = *(const f16x8*)(u5b + s * 32);
      const f16x8 e0 = *(const f16x8*)&seb[buf][m][s * 32 + quad * 8];
      // w = eb * max(ui5*uj5, ui*uj)  — packed f16, whole-vector ops
      const f16x8 a0 = e0 * __builtin_elementwise_max(u58 * uj58, ui8 * uj8);
      #pragma unroll
      for (int dt = 0; dt < 4; dt++)
        acc[dt] = __builtin_amdgcn_mfma_f32_16x16x32_f16(a0, bc[dt], acc[dt], 0, 0, 0);
      acc[4] = __builtin_amdgcn_mfma_f32_16x16x32_f16(a0, kOne, acc[4], 0, 0, 0);
      if (s < 3) {
        #pragma unroll
        for (int dt = 0; dt < 4; dt++) bc[dt] = bn[dt];
      }
    }
    if (jc + 1 < nc) fill(buf ^ 1);        // expf + LDS write after compute
  }

  // epilogue: partials
  const size_t lb = (size_t)(chunk * 4 + h) * NN + i0;
  if (m == 0) {
    #pragma unroll
    for (int r = 0; r < 4; r++)
      L[lb + quad * 4 + r] = acc[4][r];
  }
  const size_t pbase = ((size_t)(chunk * 4 + h) * NN + i0) * 64;
  #pragma unroll
  for (int dt = 0; dt < 4; dt++)
    #pragma unroll
    for (int r = 0; r < 4; r++)
      P[pbase + (size_t)(quad * 4 + r) * 64 + dt * 16 + m] = acc[dt][r];
}

// ---- Kernel 3: reduce partials, normalize, ELU ---------------------------
// grid (256 i-tiles of 16, 4 heads), block 256.
template <int CHT>
__global__ __launch_bounds__(256) void reduce_out(
    const float* __restrict__ P, const float* __restrict__ L,
    const float* __restrict__ Wh, float* __restrict__ out) {
  const int i0 = blockIdx.x * 16;
  const int h = blockIdx.y;
  const int t = threadIdx.x;
  const int d = t & 63;
  const int isub = t >> 6;
  #pragma unroll
  for (int ii = 0; ii < 4; ii++) {
    const int i = i0 + isub * 4 + ii;
    float lsum = 0.f, s = 0.f;
    #pragma unroll
    for (int c = 0; c < CHT; c++) {
      lsum += L[(size_t)(c * 4 + h) * NN + i];
      s += P[((size_t)(c * 4 + h) * NN + i) * 64 + d];
    }
    const float wh = Wh[(size_t)i * 256 + h * 64 + d];
    const bool fb = (lsum == 0.f);
    float o = fb ? wh : s / lsum;
    o = (o > 0.f) ? o : (__expf(o) - 1.f);
    out[(size_t)i * 256 + h * 64 + d] = o;
  }
}

extern "C" void kernel_launch(void* const* d_in, const int* in_sizes, int n_in,
                              void* d_out, int out_size, void* d_ws, size_t ws_size,
                              hipStream_t stream) {
  const float* h_in = (const float*)d_in[0];   // (4096, 256)
  const float* adj  = (const float*)d_in[1];   // (4096, 4096)
  const float* W    = (const float*)d_in[2];   // (256, 256)
  const float* a    = (const float*)d_in[3];   // (4, 128)
  float* out = (float*)d_out;
  float* ws = (float*)d_ws;

  int CH = 8;
  while (CH > 1) {
    size_t floats = 1048576 /*Wh*/ + 524288 /*Vt f16*/ + 32768 /*u arrays*/ +
                    (size_t)CH * (16384 + 1048576);
    if (floats * 4 <= ws_size) break;
    CH >>= 1;
  }
  const int jpc = NN / CH;

  float* Wh = ws;
  _Float16* Vt   = (_Float16*)(ws + 1048576);
  _Float16* uit  = (_Float16*)(ws + 1048576 + 524288);
  _Float16* ui5t = uit + 16384;
  _Float16* ujt  = ui5t + 16384;
  _Float16* uj5t = ujt + 16384;
  float* Lb = ws + 1048576 + 524288 + 32768;
  float* Pb = Lb + (size_t)CH * 16384;

  hipLaunchKernelGGL(gemm_wh, dim3(4, 128), dim3(256), 0, stream,
                     h_in, W, a, Wh, Vt, uit, ui5t, ujt, uj5t);
  hipLaunchKernelGGL(gat_attn, dim3(256, CH), dim3(256), 0, stream,
                     adj, Vt, uit, ui5t, ujt, uj5t, Pb, Lb, jpc);
  switch (CH) {
    case 8: hipLaunchKernelGGL((reduce_out<8>), dim3(256, 4), dim3(256), 0, stream, Pb, Lb, Wh, out); break;
    case 4: hipLaunchKernelGGL((reduce_out<4>), dim3(256, 4), dim3(256), 0, stream, Pb, Lb, Wh, out); break;
    case 2: hipLaunchKernelGGL((reduce_out<2>), dim3(256, 4), dim3(256), 0, stream, Pb, Lb, Wh, out); break;
    default: hipLaunchKernelGGL((reduce_out<1>), dim3(256, 4), dim3(256), 0, stream, Pb, Lb, Wh, out); break;
  }
}

// Round 2
// 185.037 us; speedup vs baseline: 1.5224x; 1.5224x over previous
//
#include <hip/hip_runtime.h>
#include <cstdint>
#include <cstddef>

// DenseGAT, N=4096, IN_DIM=256, H=4, D=64, NEG_SLOPE=0.2
// w[i,j,h] = eb * max(t5, tt);  tt = ui*uj = exp(.2(ei+ej)),
//   t5 = ui5*uj5 = exp(ei+ej) = tt^5 (exact inputs), eb = exp(bias) or 0.
// max trick: tt>1 => t5>tt, tt<1 => t5<tt, so select == max. Row sums via
// an extra MFMA against a ones-B fragment (no serial VALU add chain).
//
// R1 post-mortem: __launch_bounds__(256,8) capped unified VGPR+AGPR at 64;
//   allocator spilled bc/bn/pf to scratch (FETCH 41->237MB, WRITE 33->280MB).
// R2: keep 16-row i-tile (grid 2048 = 8 blocks/CU available) + async-stage
//   split, but launch_bounds(256,4) (128-reg cap, no spill) and drop the
//   manual bn[] double-buffer (-16 forced-live VGPRs; compiler schedules).

typedef _Float16 f16x4 __attribute__((ext_vector_type(4)));
typedef _Float16 f16x8 __attribute__((ext_vector_type(8)));
typedef float f32x4 __attribute__((ext_vector_type(4)));

#define NN 4096

// ---- Kernel 1: Wh = h @ W (fp32) + Vt (fp16 transpose) + ui/uj exps ------
// grid (4 heads, 128 row-tiles of 32), block 256.
__global__ __launch_bounds__(256) void gemm_wh(
    const float* __restrict__ A, const float* __restrict__ Bw,
    const float* __restrict__ av, float* __restrict__ C,
    _Float16* __restrict__ Vt,
    _Float16* __restrict__ uit, _Float16* __restrict__ ui5t,
    _Float16* __restrict__ ujt, _Float16* __restrict__ uj5t) {
  __shared__ float sA[32][36];      // [k][row]
  __shared__ float sB[32][68];      // [k][col]
  __shared__ _Float16 sT[64][40];   // transpose staging
  const int h  = blockIdx.x;
  const int by = blockIdx.y;
  const int t  = threadIdx.x;
  const int row0 = by * 32, col0 = h * 64;
  const int tc = t & 15, tr = t >> 4;      // cols tc*4..+3, rows tr*2..+1
  float acc[2][4];
  #pragma unroll
  for (int q = 0; q < 2; q++)
    #pragma unroll
    for (int p = 0; p < 4; p++) acc[q][p] = 0.f;

  for (int k0 = 0; k0 < 256; k0 += 32) {
    __syncthreads();
    {
      const int r = t >> 3, k4 = (t & 7) * 4;      // A: 32x32
      float4 v = *(const float4*)&A[(size_t)(row0 + r) * 256 + k0 + k4];
      sA[k4 + 0][r] = v.x; sA[k4 + 1][r] = v.y;
      sA[k4 + 2][r] = v.z; sA[k4 + 3][r] = v.w;
    }
    #pragma unroll
    for (int q = 0; q < 2; q++) {                   // B: 32x64
      const int u = t + q * 256;
      const int kr = u >> 4, c4 = (u & 15) * 4;
      *(float4*)&sB[kr][c4] =
          *(const float4*)&Bw[(size_t)(k0 + kr) * 256 + col0 + c4];
    }
    __syncthreads();
    #pragma unroll
    for (int kk = 0; kk < 32; kk++) {
      float2 a2 = *(const float2*)&sA[kk][tr * 2];
      float4 bv = *(const float4*)&sB[kk][tc * 4];
      const float bp[4] = {bv.x, bv.y, bv.z, bv.w};
      #pragma unroll
      for (int p = 0; p < 4; p++) {
        acc[0][p] = fmaf(a2.x, bp[p], acc[0][p]);
        acc[1][p] = fmaf(a2.y, bp[p], acc[1][p]);
      }
    }
  }
  // C store (fp32 Wh)
  #pragma unroll
  for (int q = 0; q < 2; q++) {
    float4 v = make_float4(acc[q][0], acc[q][1], acc[q][2], acc[q][3]);
    *(float4*)&C[(size_t)(row0 + tr * 2 + q) * 256 + col0 + tc * 4] = v;
  }
  // ei/ej: dot with a_i, a_j over the 64 cols of this head
  {
    float pi[2] = {0.f, 0.f}, pj[2] = {0.f, 0.f};
    #pragma unroll
    for (int q = 0; q < 2; q++)
      #pragma unroll
      for (int p = 0; p < 4; p++) {
        const int d = tc * 4 + p;
        pi[q] = fmaf(acc[q][p], av[h * 128 + d], pi[q]);
        pj[q] = fmaf(acc[q][p], av[h * 128 + 64 + d], pj[q]);
      }
    #pragma unroll
    for (int m = 1; m <= 8; m <<= 1) {
      #pragma unroll
      for (int q = 0; q < 2; q++) {
        pi[q] += __shfl_xor(pi[q], m, 64);
        pj[q] += __shfl_xor(pj[q], m, 64);
      }
    }
    if (tc == 0) {
      #pragma unroll
      for (int q = 0; q < 2; q++) {
        const int row = row0 + tr * 2 + q;
        uit [(size_t)h * NN + row] = (_Float16)__expf(0.2f * pi[q]);
        ui5t[(size_t)h * NN + row] = (_Float16)__expf(pi[q]);       // = ui^5
        ujt [(size_t)h * NN + row] = (_Float16)__expf(0.2f * pj[q]);
        uj5t[(size_t)h * NN + row] = (_Float16)__expf(pj[q]);       // = uj^5
      }
    }
  }
  // Vt transpose: Vt[col0+d][row0+j] fp16
  #pragma unroll
  for (int q = 0; q < 2; q++)
    #pragma unroll
    for (int p = 0; p < 4; p++)
      sT[tc * 4 + p][tr * 2 + q] = (_Float16)acc[q][p];
  __syncthreads();
  {
    const int dd = t >> 2, j8 = (t & 3) * 8;
    f16x8 w;
    #pragma unroll
    for (int k = 0; k < 8; k++) w[k] = sT[dd][j8 + k];
    *(f16x8*)&Vt[(size_t)(col0 + dd) * NN + row0 + j8] = w;
  }
}

// ---- Kernel 2: fused masked-softmax attention (MFMA) ---------------------
// grid (256 i-tiles of 16, CH j-chunks), block 256 = 4 waves (wave = head).
__global__ __launch_bounds__(256, 4) void gat_attn(
    const float* __restrict__ bias, const _Float16* __restrict__ Vt,
    const _Float16* __restrict__ uit, const _Float16* __restrict__ ui5t,
    const _Float16* __restrict__ ujt, const _Float16* __restrict__ uj5t,
    float* __restrict__ P, float* __restrict__ L, int jpc) {
  __shared__ _Float16 seb[2][16][136];   // exp(bias) tile [i][j], pad 8
  const int itile = blockIdx.x;
  const int chunk = blockIdx.y;
  const int tid = threadIdx.x;
  const int lane = tid & 63;
  const int h = __builtin_amdgcn_readfirstlane(tid >> 6);
  const int m = lane & 15;
  const int quad = lane >> 4;
  const int i0 = itile * 16;
  const int j0 = chunk * jpc;
  const int nc = jpc >> 7;

  f32x4 acc[5];                          // [dt0..3, ones-col]
  #pragma unroll
  for (int dt = 0; dt < 5; dt++)
    #pragma unroll
    for (int r = 0; r < 4; r++) acc[dt][r] = 0.f;

  const _Float16 ui_v = uit [(size_t)h * NN + i0 + m];
  const _Float16 u5_v = ui5t[(size_t)h * NN + i0 + m];
  const f16x8 ui8 = {ui_v, ui_v, ui_v, ui_v, ui_v, ui_v, ui_v, ui_v};
  const f16x8 u58 = {u5_v, u5_v, u5_v, u5_v, u5_v, u5_v, u5_v, u5_v};
  const f16x8 kOne = {(_Float16)1.f, (_Float16)1.f, (_Float16)1.f, (_Float16)1.f,
                      (_Float16)1.f, (_Float16)1.f, (_Float16)1.f, (_Float16)1.f};

  // async-stage split: load_chunk issues the bias loads into regs; fill
  // consumes them (expf + LDS write) only after the compute phase.
  const int sr = tid >> 4, sf = tid & 15;   // 16 rows x (16 thr * 8 cols)
  const float* bp0 = bias + (size_t)(i0 + sr) * NN + j0 + sf * 4;
  float4 pf0, pf1;
  auto load_chunk = [&](int jc) {
    const float* bp = bp0 + jc * 128;
    pf0 = *(const float4*)(bp);
    pf1 = *(const float4*)(bp + 64);
  };
  auto fill = [&](int buf) {
    f16x4 e0v, e1v;
    e0v[0] = (_Float16)((pf0.x == 0.f) ? 0.f : __expf(pf0.x));
    e0v[1] = (_Float16)((pf0.y == 0.f) ? 0.f : __expf(pf0.y));
    e0v[2] = (_Float16)((pf0.z == 0.f) ? 0.f : __expf(pf0.z));
    e0v[3] = (_Float16)((pf0.w == 0.f) ? 0.f : __expf(pf0.w));
    e1v[0] = (_Float16)((pf1.x == 0.f) ? 0.f : __expf(pf1.x));
    e1v[1] = (_Float16)((pf1.y == 0.f) ? 0.f : __expf(pf1.y));
    e1v[2] = (_Float16)((pf1.z == 0.f) ? 0.f : __expf(pf1.z));
    e1v[3] = (_Float16)((pf1.w == 0.f) ? 0.f : __expf(pf1.w));
    *(f16x4*)&seb[buf][sr][sf * 4] = e0v;
    *(f16x4*)&seb[buf][sr][sf * 4 + 64] = e1v;
  };

  load_chunk(0);
  fill(0);

  for (int jc = 0; jc < nc; jc++) {
    const int buf = jc & 1;
    __syncthreads();
    if (jc + 1 < nc) load_chunk(jc + 1);   // issue early, consume late

    const _Float16* vb  = Vt + (size_t)(h * 64 + m) * NN + j0 + jc * 128 + quad * 8;
    const _Float16* ujb = ujt  + (size_t)h * NN + j0 + jc * 128 + quad * 8;
    const _Float16* u5b = uj5t + (size_t)h * NN + j0 + jc * 128 + quad * 8;

    #pragma unroll
    for (int s = 0; s < 4; s++) {
      f16x8 bc[4];
      #pragma unroll
      for (int dt = 0; dt < 4; dt++)
        bc[dt] = *(const f16x8*)(vb + (size_t)(dt * 16) * NN + s * 32);
      const f16x8 uj8  = *(const f16x8*)(ujb + s * 32);
      const f16x8 uj58 = *(const f16x8*)(u5b + s * 32);
      const f16x8 e0 = *(const f16x8*)&seb[buf][m][s * 32 + quad * 8];
      // w = eb * max(ui5*uj5, ui*uj)  — packed f16, whole-vector ops
      const f16x8 a0 = e0 * __builtin_elementwise_max(u58 * uj58, ui8 * uj8);
      #pragma unroll
      for (int dt = 0; dt < 4; dt++)
        acc[dt] = __builtin_amdgcn_mfma_f32_16x16x32_f16(a0, bc[dt], acc[dt], 0, 0, 0);
      acc[4] = __builtin_amdgcn_mfma_f32_16x16x32_f16(a0, kOne, acc[4], 0, 0, 0);
    }
    if (jc + 1 < nc) fill(buf ^ 1);        // expf + LDS write after compute
  }

  // epilogue: partials
  const size_t lb = (size_t)(chunk * 4 + h) * NN + i0;
  if (m == 0) {
    #pragma unroll
    for (int r = 0; r < 4; r++)
      L[lb + quad * 4 + r] = acc[4][r];
  }
  const size_t pbase = ((size_t)(chunk * 4 + h) * NN + i0) * 64;
  #pragma unroll
  for (int dt = 0; dt < 4; dt++)
    #pragma unroll
    for (int r = 0; r < 4; r++)
      P[pbase + (size_t)(quad * 4 + r) * 64 + dt * 16 + m] = acc[dt][r];
}

// ---- Kernel 3: reduce partials, normalize, ELU ---------------------------
// grid (256 i-tiles of 16, 4 heads), block 256.
template <int CHT>
__global__ __launch_bounds__(256) void reduce_out(
    const float* __restrict__ P, const float* __restrict__ L,
    const float* __restrict__ Wh, float* __restrict__ out) {
  const int i0 = blockIdx.x * 16;
  const int h = blockIdx.y;
  const int t = threadIdx.x;
  const int d = t & 63;
  const int isub = t >> 6;
  #pragma unroll
  for (int ii = 0; ii < 4; ii++) {
    const int i = i0 + isub * 4 + ii;
    float lsum = 0.f, s = 0.f;
    #pragma unroll
    for (int c = 0; c < CHT; c++) {
      lsum += L[(size_t)(c * 4 + h) * NN + i];
      s += P[((size_t)(c * 4 + h) * NN + i) * 64 + d];
    }
    const float wh = Wh[(size_t)i * 256 + h * 64 + d];
    const bool fb = (lsum == 0.f);
    float o = fb ? wh : s / lsum;
    o = (o > 0.f) ? o : (__expf(o) - 1.f);
    out[(size_t)i * 256 + h * 64 + d] = o;
  }
}

extern "C" void kernel_launch(void* const* d_in, const int* in_sizes, int n_in,
                              void* d_out, int out_size, void* d_ws, size_t ws_size,
                              hipStream_t stream) {
  const float* h_in = (const float*)d_in[0];   // (4096, 256)
  const float* adj  = (const float*)d_in[1];   // (4096, 4096)
  const float* W    = (const float*)d_in[2];   // (256, 256)
  const float* a    = (const float*)d_in[3];   // (4, 128)
  float* out = (float*)d_out;
  float* ws = (float*)d_ws;

  int CH = 8;
  while (CH > 1) {
    size_t floats = 1048576 /*Wh*/ + 524288 /*Vt f16*/ + 32768 /*u arrays*/ +
                    (size_t)CH * (16384 + 1048576);
    if (floats * 4 <= ws_size) break;
    CH >>= 1;
  }
  const int jpc = NN / CH;

  float* Wh = ws;
  _Float16* Vt   = (_Float16*)(ws + 1048576);
  _Float16* uit  = (_Float16*)(ws + 1048576 + 524288);
  _Float16* ui5t = uit + 16384;
  _Float16* ujt  = ui5t + 16384;
  _Float16* uj5t = ujt + 16384;
  float* Lb = ws + 1048576 + 524288 + 32768;
  float* Pb = Lb + (size_t)CH * 16384;

  hipLaunchKernelGGL(gemm_wh, dim3(4, 128), dim3(256), 0, stream,
                     h_in, W, a, Wh, Vt, uit, ui5t, ujt, uj5t);
  hipLaunchKernelGGL(gat_attn, dim3(256, CH), dim3(256), 0, stream,
                     adj, Vt, uit, ui5t, ujt, uj5t, Pb, Lb, jpc);
  switch (CH) {
    case 8: hipLaunchKernelGGL((reduce_out<8>), dim3(256, 4), dim3(256), 0, stream, Pb, Lb, Wh, out); break;
    case 4: hipLaunchKernelGGL((reduce_out<4>), dim3(256, 4), dim3(256), 0, stream, Pb, Lb, Wh, out); break;
    case 2: hipLaunchKernelGGL((reduce_out<2>), dim3(256, 4), dim3(256), 0, stream, Pb, Lb, Wh, out); break;
    default: hipLaunchKernelGGL((reduce_out<1>), dim3(256, 4), dim3(256), 0, stream, Pb, Lb, Wh, out); break;
  }
}